// Round 4
// baseline (530.270 us; speedup 1.0000x reference)
//
#include <hip/hip_runtime.h>
#include <cfloat>

#define M_UP   32768
#define N_DOWN 8192
#define UPC    128
#define DOWNC  256
#define OUTC   128
#define NCHUNK 8
#define CHUNK  (N_DOWN / NCHUNK)   // 1024
#define G      8                   // selection group size
#define Q      2                   // queries per thread (amortizes LDS reads)

__device__ __forceinline__ void fma4(float4& acc, float s, const float4 w) {
    acc.x = fmaf(s, w.x, acc.x);
    acc.y = fmaf(s, w.y, acc.y);
    acc.z = fmaf(s, w.z, acc.z);
    acc.w = fmaf(s, w.w, acc.w);
}

// Branchless stable top-3 insert with index tracking.
// Strict < everywhere => earlier-inserted wins ties (stable in scan order),
// matching jax.lax.top_k's lower-index-first tie-break.
__device__ __forceinline__ void top3_bl(float s, int idx,
                                        float& d0, float& d1, float& d2,
                                        int& i0, int& i1, int& i2) {
    bool c0 = s < d0, c1 = s < d1, c2 = s < d2;
    float n0 = fminf(d0, s);
    float n1 = __builtin_amdgcn_fmed3f(d0, d1, s);
    float n2 = __builtin_amdgcn_fmed3f(d1, d2, s);
    int m0 = c0 ? idx : i0;
    int m1 = c0 ? i0 : (c1 ? idx : i1);
    int m2 = c1 ? i1 : (c2 ? idx : i2);
    d0 = n0; d1 = n1; d2 = n2;
    i0 = m0; i1 = m1; i2 = m2;
}

// ---------------------------------------------------------------------------
// K0: transpose weights for coalesced float4 GEMM reads.
// ---------------------------------------------------------------------------
__global__ __launch_bounds__(256) void transpose_w(
        const float* __restrict__ W_up, const float* __restrict__ W_down,
        float* __restrict__ wt_up, float* __restrict__ wt_down) {
    int e = blockIdx.x * 256 + threadIdx.x;
    if (e < DOWNC * OUTC) {
        int k = e >> 7, c = e & 127;
        wt_down[e] = W_down[c * DOWNC + k];
    } else {
        int e2 = e - DOWNC * OUTC;
        int k = e2 >> 7, c = e2 & 127;
        wt_up[e2] = W_up[c * UPC + k];
    }
}

// ---------------------------------------------------------------------------
// K1: down_f = down_features @ W_down.T + b_down  (8192 x 128)
// R3 was latency-bound (VGPR=36 -> ~2 A-loads in flight, ~900cy exposed per
// k4-step, only 2 waves/SIMD). Fix: K-super-steps of 32 that issue 16
// independent A-loads into named register buffers before the FMA burst ->
// 8 stalls/wave instead of 64.
// ---------------------------------------------------------------------------
__global__ __launch_bounds__(256) void down_proj(
        const float* __restrict__ A, const float* __restrict__ WT,
        const float* __restrict__ bias, float* __restrict__ down_f) {
    const int c4 = threadIdx.x & 31;
    const int rr = threadIdx.x >> 5;
    const int r0 = blockIdx.x * 16 + rr;
    const int r1 = r0 + 8;
    const float* A0 = A + r0 * DOWNC;
    const float* A1 = A + r1 * DOWNC;
    float4 acc0 = {0.f, 0.f, 0.f, 0.f};
    float4 acc1 = {0.f, 0.f, 0.f, 0.f};
    #pragma unroll
    for (int ss = 0; ss < DOWNC / 32; ++ss) {      // 8 super-steps
        const int kb = ss * 32;
        float4 a0b[8], a1b[8];
        #pragma unroll
        for (int i = 0; i < 8; ++i) {              // 16 loads in flight
            a0b[i] = *(const float4*)(A0 + kb + 4 * i);
            a1b[i] = *(const float4*)(A1 + kb + 4 * i);
        }
        #pragma unroll
        for (int i = 0; i < 8; ++i) {
            const int k = kb + 4 * i;
            const float4* wp = (const float4*)(WT + k * OUTC) + c4;
            float4 w0 = wp[0], w1 = wp[32], w2 = wp[64], w3 = wp[96];
            fma4(acc0, a0b[i].x, w0); fma4(acc0, a0b[i].y, w1);
            fma4(acc0, a0b[i].z, w2); fma4(acc0, a0b[i].w, w3);
            fma4(acc1, a1b[i].x, w0); fma4(acc1, a1b[i].y, w1);
            fma4(acc1, a1b[i].z, w2); fma4(acc1, a1b[i].w, w3);
        }
    }
    float4 b = ((const float4*)bias)[c4];
    acc0.x += b.x; acc0.y += b.y; acc0.z += b.z; acc0.w += b.w;
    acc1.x += b.x; acc1.y += b.y; acc1.z += b.z; acc1.w += b.w;
    ((float4*)down_f)[r0 * 32 + c4] = acc0;
    ((float4*)down_f)[r1 * 32 + c4] = acc1;
}

// ---------------------------------------------------------------------------
// K2: partial 3-NN (unchanged from R3 — verified). Q=2 queries/thread + SoA
// LDS chunk: 1.57M wave-level b128 reads vs a ~28us VALU floor.
// Group-min top-3 selection + exact refine of <=3 winning groups per query.
// Partials stored as (d, idx-as-float) float2 pairs.
// ---------------------------------------------------------------------------
__global__ __launch_bounds__(256) void knn_partial(
        const float* __restrict__ up_points,
        const float* __restrict__ down_points,
        float2* __restrict__ part) {            // [NCHUNK][M_UP][3]
    __shared__ __align__(16) float sx[CHUNK];
    __shared__ __align__(16) float sy[CHUNK];
    __shared__ __align__(16) float sz[CHUNK];
    const int base = blockIdx.y * CHUNK;
    for (int t = threadIdx.x; t < CHUNK; t += 256) {
        int g = base + t;
        sx[t] = down_points[3 * g];
        sy[t] = down_points[3 * g + 1];
        sz[t] = down_points[3 * g + 2];
    }
    __syncthreads();

    const int m0 = blockIdx.x * (256 * Q) + threadIdx.x;
    const int m1 = m0 + 256;
    const float q0x = up_points[3 * m0];
    const float q0y = up_points[3 * m0 + 1];
    const float q0z = up_points[3 * m0 + 2];
    const float q1x = up_points[3 * m1];
    const float q1y = up_points[3 * m1 + 1];
    const float q1z = up_points[3 * m1 + 2];

    float a_gd0 = FLT_MAX, a_gd1 = FLT_MAX, a_gd2 = FLT_MAX;
    int   a_gi0 = 0, a_gi1 = 0, a_gi2 = 0;
    float b_gd0 = FLT_MAX, b_gd1 = FLT_MAX, b_gd2 = FLT_MAX;
    int   b_gi0 = 0, b_gi1 = 0, b_gi2 = 0;

    for (int g = 0; g < CHUNK; g += G) {
        float4 x0 = *(const float4*)&sx[g], x1 = *(const float4*)&sx[g + 4];
        float4 y0 = *(const float4*)&sy[g], y1 = *(const float4*)&sy[g + 4];
        float4 z0 = *(const float4*)&sz[g], z1 = *(const float4*)&sz[g + 4];
        float px[G] = {x0.x, x0.y, x0.z, x0.w, x1.x, x1.y, x1.z, x1.w};
        float py[G] = {y0.x, y0.y, y0.z, y0.w, y1.x, y1.y, y1.z, y1.w};
        float pz[G] = {z0.x, z0.y, z0.z, z0.w, z1.x, z1.y, z1.z, z1.w};
        float s0[G], s1[G];
        #pragma unroll
        for (int j = 0; j < G; ++j) {
            float dx0 = q0x - px[j], dy0 = q0y - py[j], dz0 = q0z - pz[j];
            s0[j] = fmaf(dz0, dz0, fmaf(dy0, dy0, dx0 * dx0));
            float dx1 = q1x - px[j], dy1 = q1y - py[j], dz1 = q1z - pz[j];
            s1[j] = fmaf(dz1, dz1, fmaf(dy1, dy1, dx1 * dx1));
        }
        float gm0 = fminf(fminf(fminf(s0[0], s0[1]), fminf(s0[2], s0[3])),
                          fminf(fminf(s0[4], s0[5]), fminf(s0[6], s0[7])));
        float gm1 = fminf(fminf(fminf(s1[0], s1[1]), fminf(s1[2], s1[3])),
                          fminf(fminf(s1[4], s1[5]), fminf(s1[6], s1[7])));
        top3_bl(gm0, g, a_gd0, a_gd1, a_gd2, a_gi0, a_gi1, a_gi2);
        top3_bl(gm1, g, b_gd0, b_gd1, b_gd2, b_gi0, b_gi1, b_gi2);
    }

    // exact refine over the 3 winning groups (24 points per query)
    #pragma unroll
    for (int qq = 0; qq < Q; ++qq) {
        const float qx = qq ? q1x : q0x;
        const float qy = qq ? q1y : q0y;
        const float qz = qq ? q1z : q0z;
        int bases[3];
        if (qq == 0) { bases[0] = a_gi0; bases[1] = a_gi1; bases[2] = a_gi2; }
        else         { bases[0] = b_gi0; bases[1] = b_gi1; bases[2] = b_gi2; }
        float D0 = FLT_MAX, D1 = FLT_MAX, D2 = FLT_MAX;
        int I0 = 0, I1 = 0, I2 = 0;
        #pragma unroll
        for (int t = 0; t < 3; ++t) {
            const int b = bases[t];
            float4 x0 = *(const float4*)&sx[b], x1 = *(const float4*)&sx[b + 4];
            float4 y0 = *(const float4*)&sy[b], y1 = *(const float4*)&sy[b + 4];
            float4 z0 = *(const float4*)&sz[b], z1 = *(const float4*)&sz[b + 4];
            float px[G] = {x0.x, x0.y, x0.z, x0.w, x1.x, x1.y, x1.z, x1.w};
            float py[G] = {y0.x, y0.y, y0.z, y0.w, y1.x, y1.y, y1.z, y1.w};
            float pz[G] = {z0.x, z0.y, z0.z, z0.w, z1.x, z1.y, z1.z, z1.w};
            #pragma unroll
            for (int j = 0; j < G; ++j) {
                float dx = qx - px[j], dy = qy - py[j], dz = qz - pz[j];
                float s = fmaf(dz, dz, fmaf(dy, dy, dx * dx));
                top3_bl(s, base + b + j, D0, D1, D2, I0, I1, I2);
            }
        }
        const int m = qq ? m1 : m0;
        const int o = (blockIdx.y * M_UP + m) * 3;
        part[o]     = make_float2(D0, __int_as_float(I0));
        part[o + 1] = make_float2(D1, __int_as_float(I1));
        part[o + 2] = make_float2(D2, __int_as_float(I2));
    }
}

// ---------------------------------------------------------------------------
// K3: fused up-projection + top-3 merge + interpolation + bias + add.
// R3: 82us, VALUBusy 24%, VGPR 36 -> latency-bound on the streamed A row.
// Fix: 8 K-super-steps (UPC/16); each issues 8 A-loads into named register
// buffers + the 6 part-loads of chunk ss, then runs the 128-FMA burst, then
// merges chunk ss (order (s,j) ascending preserved -> same tie-break).
// Epilogue issues all 6 down_f gathers together.
// ---------------------------------------------------------------------------
__global__ __launch_bounds__(256) void up_fused(
        const float* __restrict__ A, const float* __restrict__ WT,
        const float* __restrict__ bias, const float* __restrict__ down_f,
        const float2* __restrict__ part,
        float* __restrict__ out) {
    const int c4 = threadIdx.x & 31;
    const int rr = threadIdx.x >> 5;
    const int q0 = blockIdx.x * 16 + rr;
    const int q1 = q0 + 8;
    const float* A0 = A + q0 * UPC;
    const float* A1 = A + q1 * UPC;
    float4 acc0 = {0.f, 0.f, 0.f, 0.f};
    float4 acc1 = {0.f, 0.f, 0.f, 0.f};
    float D0a = FLT_MAX, D1a = FLT_MAX, D2a = FLT_MAX;
    int   I0a = 0, I1a = 0, I2a = 0;
    float D0b = FLT_MAX, D1b = FLT_MAX, D2b = FLT_MAX;
    int   I0b = 0, I1b = 0, I2b = 0;

    static_assert(NCHUNK == UPC / 16, "merge interleave assumes 8 super-steps");
    #pragma unroll
    for (int ss = 0; ss < NCHUNK; ++ss) {
        const int kb = ss * 16;
        float4 a0b[4], a1b[4];
        #pragma unroll
        for (int i = 0; i < 4; ++i) {              // 8 A-loads in flight
            a0b[i] = *(const float4*)(A0 + kb + 4 * i);
            a1b[i] = *(const float4*)(A1 + kb + 4 * i);
        }
        const float2* pa = part + (ss * M_UP + q0) * 3;
        const float2* pb = part + (ss * M_UP + q1) * 3;
        float2 va0 = pa[0], va1 = pa[1], va2 = pa[2];
        float2 vb0 = pb[0], vb1 = pb[1], vb2 = pb[2];
        #pragma unroll
        for (int i = 0; i < 4; ++i) {
            const int k = kb + 4 * i;
            const float4* wp = (const float4*)(WT + k * OUTC) + c4;
            float4 w0 = wp[0], w1 = wp[32], w2 = wp[64], w3 = wp[96];
            fma4(acc0, a0b[i].x, w0); fma4(acc0, a0b[i].y, w1);
            fma4(acc0, a0b[i].z, w2); fma4(acc0, a0b[i].w, w3);
            fma4(acc1, a1b[i].x, w0); fma4(acc1, a1b[i].y, w1);
            fma4(acc1, a1b[i].z, w2); fma4(acc1, a1b[i].w, w3);
        }
        top3_bl(va0.x, __float_as_int(va0.y), D0a, D1a, D2a, I0a, I1a, I2a);
        top3_bl(va1.x, __float_as_int(va1.y), D0a, D1a, D2a, I0a, I1a, I2a);
        top3_bl(va2.x, __float_as_int(va2.y), D0a, D1a, D2a, I0a, I1a, I2a);
        top3_bl(vb0.x, __float_as_int(vb0.y), D0b, D1b, D2b, I0b, I1b, I2b);
        top3_bl(vb1.x, __float_as_int(vb1.y), D0b, D1b, D2b, I0b, I1b, I2b);
        top3_bl(vb2.x, __float_as_int(vb2.y), D0b, D1b, D2b, I0b, I1b, I2b);
    }

    const float4 b = ((const float4*)bias)[c4];
    const float4* df4 = (const float4*)down_f;
    // issue all 6 gathers together (independent)
    float4 f0a = df4[I0a * 32 + c4];
    float4 f1a = df4[I1a * 32 + c4];
    float4 f2a = df4[I2a * 32 + c4];
    float4 f0b = df4[I0b * 32 + c4];
    float4 f1b = df4[I1b * 32 + c4];
    float4 f2b = df4[I2b * 32 + c4];

    {
        float r0 = 1.f / (D0a + 1e-8f);
        float r1 = 1.f / (D1a + 1e-8f);
        float r2 = 1.f / (D2a + 1e-8f);
        float rs = (r0 + r1) + r2;
        float w0 = r0 / rs, w1 = r1 / rs, w2 = r2 / rs;
        float4 res;
        res.x = acc0.x + b.x + fmaf(w0, f0a.x, fmaf(w1, f1a.x, w2 * f2a.x));
        res.y = acc0.y + b.y + fmaf(w0, f0a.y, fmaf(w1, f1a.y, w2 * f2a.y));
        res.z = acc0.z + b.z + fmaf(w0, f0a.z, fmaf(w1, f1a.z, w2 * f2a.z));
        res.w = acc0.w + b.w + fmaf(w0, f0a.w, fmaf(w1, f1a.w, w2 * f2a.w));
        ((float4*)out)[q0 * 32 + c4] = res;
    }
    {
        float r0 = 1.f / (D0b + 1e-8f);
        float r1 = 1.f / (D1b + 1e-8f);
        float r2 = 1.f / (D2b + 1e-8f);
        float rs = (r0 + r1) + r2;
        float w0 = r0 / rs, w1 = r1 / rs, w2 = r2 / rs;
        float4 res;
        res.x = acc1.x + b.x + fmaf(w0, f0b.x, fmaf(w1, f1b.x, w2 * f2b.x));
        res.y = acc1.y + b.y + fmaf(w0, f0b.y, fmaf(w1, f1b.y, w2 * f2b.y));
        res.z = acc1.z + b.z + fmaf(w0, f0b.z, fmaf(w1, f1b.z, w2 * f2b.z));
        res.w = acc1.w + b.w + fmaf(w0, f0b.w, fmaf(w1, f1b.w, w2 * f2b.w));
        ((float4*)out)[q1 * 32 + c4] = res;
    }
}

extern "C" void kernel_launch(void* const* d_in, const int* in_sizes, int n_in,
                              void* d_out, int out_size, void* d_ws, size_t ws_size,
                              hipStream_t stream) {
    const float* up_points     = (const float*)d_in[0];
    const float* up_features   = (const float*)d_in[1];
    const float* down_points   = (const float*)d_in[2];
    const float* down_features = (const float*)d_in[3];
    const float* W_up          = (const float*)d_in[4];
    const float* b_up          = (const float*)d_in[5];
    const float* W_down        = (const float*)d_in[6];
    const float* b_down        = (const float*)d_in[7];
    float* out = (float*)d_out;

    float* wt_down = (float*)d_ws;                         // 256*128
    float* wt_up   = wt_down + DOWNC * OUTC;               // 128*128
    float* down_f  = wt_up + UPC * OUTC;                   // 8192*128
    float2* part   = (float2*)(down_f + N_DOWN * OUTC);    // NCHUNK*32768*3 float2
    // total ~10.7 MB (same footprint as the proven R0 layout)

    transpose_w<<<(DOWNC * OUTC + UPC * OUTC) / 256, 256, 0, stream>>>(
        W_up, W_down, wt_up, wt_down);
    down_proj<<<N_DOWN / 16, 256, 0, stream>>>(
        down_features, wt_down, b_down, down_f);
    knn_partial<<<dim3(M_UP / (256 * Q), NCHUNK), 256, 0, stream>>>(
        up_points, down_points, part);
    up_fused<<<M_UP / 16, 256, 0, stream>>>(
        up_features, wt_up, b_up, down_f, part, out);
}

// Round 5
// 262.672 us; speedup vs baseline: 2.0188x; 2.0188x over previous
//
#include <hip/hip_runtime.h>
#include <cfloat>

#define M_UP   32768
#define N_DOWN 8192
#define UPC    128
#define DOWNC  256
#define OUTC   128
#define NCHUNK 8
#define CHUNK  (N_DOWN / NCHUNK)   // 1024
#define G      8                   // selection group size
#define Q      2                   // queries per thread (amortizes LDS reads)

__device__ __forceinline__ void fma4(float4& acc, float s, const float4 w) {
    acc.x = fmaf(s, w.x, acc.x);
    acc.y = fmaf(s, w.y, acc.y);
    acc.z = fmaf(s, w.z, acc.z);
    acc.w = fmaf(s, w.w, acc.w);
}

// Branchless stable top-3 insert with index tracking.
// Strict < everywhere => earlier-inserted wins ties (stable in scan order),
// matching jax.lax.top_k's lower-index-first tie-break.
__device__ __forceinline__ void top3_bl(float s, int idx,
                                        float& d0, float& d1, float& d2,
                                        int& i0, int& i1, int& i2) {
    bool c0 = s < d0, c1 = s < d1, c2 = s < d2;
    float n0 = fminf(d0, s);
    float n1 = __builtin_amdgcn_fmed3f(d0, d1, s);
    float n2 = __builtin_amdgcn_fmed3f(d1, d2, s);
    int m0 = c0 ? idx : i0;
    int m1 = c0 ? i0 : (c1 ? idx : i1);
    int m2 = c1 ? i1 : (c2 ? idx : i2);
    d0 = n0; d1 = n1; d2 = n2;
    i0 = m0; i1 = m1; i2 = m2;
}

// ---------------------------------------------------------------------------
// K0: transpose weights for coalesced float4 GEMM reads.
// ---------------------------------------------------------------------------
__global__ __launch_bounds__(256) void transpose_w(
        const float* __restrict__ W_up, const float* __restrict__ W_down,
        float* __restrict__ wt_up, float* __restrict__ wt_down) {
    int e = blockIdx.x * 256 + threadIdx.x;
    if (e < DOWNC * OUTC) {
        int k = e >> 7, c = e & 127;
        wt_down[e] = W_down[c * DOWNC + k];
    } else {
        int e2 = e - DOWNC * OUTC;
        int k = e2 >> 7, c = e2 & 127;
        wt_up[e2] = W_up[c * UPC + k];
    }
}

// ---------------------------------------------------------------------------
// K1: down_f = down_features @ W_down.T + b_down  (8192 x 128)
// Batched loads (8 dwordx4 in flight) per super-step; `#pragma unroll 1`
// fences cross-iteration hoisting (R4 lesson: full unroll -> 256 VGPR +
// 628MB scratch spill). launch_bounds(256,4) caps VGPR at 128.
// ---------------------------------------------------------------------------
__global__ __launch_bounds__(256, 4) void down_proj(
        const float* __restrict__ A, const float* __restrict__ WT,
        const float* __restrict__ bias, float* __restrict__ down_f) {
    const int c4 = threadIdx.x & 31;
    const int rr = threadIdx.x >> 5;
    const int r0 = blockIdx.x * 16 + rr;
    const int r1 = r0 + 8;
    const float* A0 = A + r0 * DOWNC;
    const float* A1 = A + r1 * DOWNC;
    float4 acc0 = {0.f, 0.f, 0.f, 0.f};
    float4 acc1 = {0.f, 0.f, 0.f, 0.f};
    #pragma unroll 1
    for (int ss = 0; ss < DOWNC / 16; ++ss) {      // 16 super-steps, no hoist
        const int kb = ss * 16;
        float4 a0b[4], a1b[4];
        #pragma unroll
        for (int i = 0; i < 4; ++i) {              // 8 loads in flight
            a0b[i] = *(const float4*)(A0 + kb + 4 * i);
            a1b[i] = *(const float4*)(A1 + kb + 4 * i);
        }
        #pragma unroll
        for (int i = 0; i < 4; ++i) {
            const int k = kb + 4 * i;
            const float4* wp = (const float4*)(WT + k * OUTC) + c4;
            float4 w0 = wp[0], w1 = wp[32], w2 = wp[64], w3 = wp[96];
            fma4(acc0, a0b[i].x, w0); fma4(acc0, a0b[i].y, w1);
            fma4(acc0, a0b[i].z, w2); fma4(acc0, a0b[i].w, w3);
            fma4(acc1, a1b[i].x, w0); fma4(acc1, a1b[i].y, w1);
            fma4(acc1, a1b[i].z, w2); fma4(acc1, a1b[i].w, w3);
        }
    }
    float4 b = ((const float4*)bias)[c4];
    acc0.x += b.x; acc0.y += b.y; acc0.z += b.z; acc0.w += b.w;
    acc1.x += b.x; acc1.y += b.y; acc1.z += b.z; acc1.w += b.w;
    ((float4*)down_f)[r0 * 32 + c4] = acc0;
    ((float4*)down_f)[r1 * 32 + c4] = acc1;
}

// ---------------------------------------------------------------------------
// K2: partial 3-NN (unchanged — verified at ~<80us). Q=2 queries/thread +
// SoA LDS chunk: 1.57M wave-level b128 reads vs a ~28us VALU floor.
// Group-min top-3 selection + exact refine of <=3 winning groups per query.
// Partials stored as (d, idx-as-float) float2 pairs.
// ---------------------------------------------------------------------------
__global__ __launch_bounds__(256) void knn_partial(
        const float* __restrict__ up_points,
        const float* __restrict__ down_points,
        float2* __restrict__ part) {            // [NCHUNK][M_UP][3]
    __shared__ __align__(16) float sx[CHUNK];
    __shared__ __align__(16) float sy[CHUNK];
    __shared__ __align__(16) float sz[CHUNK];
    const int base = blockIdx.y * CHUNK;
    for (int t = threadIdx.x; t < CHUNK; t += 256) {
        int g = base + t;
        sx[t] = down_points[3 * g];
        sy[t] = down_points[3 * g + 1];
        sz[t] = down_points[3 * g + 2];
    }
    __syncthreads();

    const int m0 = blockIdx.x * (256 * Q) + threadIdx.x;
    const int m1 = m0 + 256;
    const float q0x = up_points[3 * m0];
    const float q0y = up_points[3 * m0 + 1];
    const float q0z = up_points[3 * m0 + 2];
    const float q1x = up_points[3 * m1];
    const float q1y = up_points[3 * m1 + 1];
    const float q1z = up_points[3 * m1 + 2];

    float a_gd0 = FLT_MAX, a_gd1 = FLT_MAX, a_gd2 = FLT_MAX;
    int   a_gi0 = 0, a_gi1 = 0, a_gi2 = 0;
    float b_gd0 = FLT_MAX, b_gd1 = FLT_MAX, b_gd2 = FLT_MAX;
    int   b_gi0 = 0, b_gi1 = 0, b_gi2 = 0;

    for (int g = 0; g < CHUNK; g += G) {
        float4 x0 = *(const float4*)&sx[g], x1 = *(const float4*)&sx[g + 4];
        float4 y0 = *(const float4*)&sy[g], y1 = *(const float4*)&sy[g + 4];
        float4 z0 = *(const float4*)&sz[g], z1 = *(const float4*)&sz[g + 4];
        float px[G] = {x0.x, x0.y, x0.z, x0.w, x1.x, x1.y, x1.z, x1.w};
        float py[G] = {y0.x, y0.y, y0.z, y0.w, y1.x, y1.y, y1.z, y1.w};
        float pz[G] = {z0.x, z0.y, z0.z, z0.w, z1.x, z1.y, z1.z, z1.w};
        float s0[G], s1[G];
        #pragma unroll
        for (int j = 0; j < G; ++j) {
            float dx0 = q0x - px[j], dy0 = q0y - py[j], dz0 = q0z - pz[j];
            s0[j] = fmaf(dz0, dz0, fmaf(dy0, dy0, dx0 * dx0));
            float dx1 = q1x - px[j], dy1 = q1y - py[j], dz1 = q1z - pz[j];
            s1[j] = fmaf(dz1, dz1, fmaf(dy1, dy1, dx1 * dx1));
        }
        float gm0 = fminf(fminf(fminf(s0[0], s0[1]), fminf(s0[2], s0[3])),
                          fminf(fminf(s0[4], s0[5]), fminf(s0[6], s0[7])));
        float gm1 = fminf(fminf(fminf(s1[0], s1[1]), fminf(s1[2], s1[3])),
                          fminf(fminf(s1[4], s1[5]), fminf(s1[6], s1[7])));
        top3_bl(gm0, g, a_gd0, a_gd1, a_gd2, a_gi0, a_gi1, a_gi2);
        top3_bl(gm1, g, b_gd0, b_gd1, b_gd2, b_gi0, b_gi1, b_gi2);
    }

    // exact refine over the 3 winning groups (24 points per query)
    #pragma unroll
    for (int qq = 0; qq < Q; ++qq) {
        const float qx = qq ? q1x : q0x;
        const float qy = qq ? q1y : q0y;
        const float qz = qq ? q1z : q0z;
        int bases[3];
        if (qq == 0) { bases[0] = a_gi0; bases[1] = a_gi1; bases[2] = a_gi2; }
        else         { bases[0] = b_gi0; bases[1] = b_gi1; bases[2] = b_gi2; }
        float D0 = FLT_MAX, D1 = FLT_MAX, D2 = FLT_MAX;
        int I0 = 0, I1 = 0, I2 = 0;
        #pragma unroll
        for (int t = 0; t < 3; ++t) {
            const int b = bases[t];
            float4 x0 = *(const float4*)&sx[b], x1 = *(const float4*)&sx[b + 4];
            float4 y0 = *(const float4*)&sy[b], y1 = *(const float4*)&sy[b + 4];
            float4 z0 = *(const float4*)&sz[b], z1 = *(const float4*)&sz[b + 4];
            float px[G] = {x0.x, x0.y, x0.z, x0.w, x1.x, x1.y, x1.z, x1.w};
            float py[G] = {y0.x, y0.y, y0.z, y0.w, y1.x, y1.y, y1.z, y1.w};
            float pz[G] = {z0.x, z0.y, z0.z, z0.w, z1.x, z1.y, z1.z, z1.w};
            #pragma unroll
            for (int j = 0; j < G; ++j) {
                float dx = qx - px[j], dy = qy - py[j], dz = qz - pz[j];
                float s = fmaf(dz, dz, fmaf(dy, dy, dx * dx));
                top3_bl(s, base + b + j, D0, D1, D2, I0, I1, I2);
            }
        }
        const int m = qq ? m1 : m0;
        const int o = (blockIdx.y * M_UP + m) * 3;
        part[o]     = make_float2(D0, __int_as_float(I0));
        part[o + 1] = make_float2(D1, __int_as_float(I1));
        part[o + 2] = make_float2(D2, __int_as_float(I2));
    }
}

// ---------------------------------------------------------------------------
// K3: fused up-projection + top-3 merge + interpolation + bias + add.
// R3 (82us): latency-bound, ~2 loads in flight. R4: full unroll -> 256 VGPR,
// scratch spill, 420us. R5: batched loads (8 A-dwordx4 + 6 part-dwordx2 in
// flight per super-step) with `#pragma unroll 1` fencing the depth and
// launch_bounds(256,4) capping VGPR at 128 (4 waves/SIMD).
// Merge insert order (ss,j) ascending preserved -> same tie-break semantics.
// ---------------------------------------------------------------------------
__global__ __launch_bounds__(256, 4) void up_fused(
        const float* __restrict__ A, const float* __restrict__ WT,
        const float* __restrict__ bias, const float* __restrict__ down_f,
        const float2* __restrict__ part,
        float* __restrict__ out) {
    const int c4 = threadIdx.x & 31;
    const int rr = threadIdx.x >> 5;
    const int q0 = blockIdx.x * 16 + rr;
    const int q1 = q0 + 8;
    const float* A0 = A + q0 * UPC;
    const float* A1 = A + q1 * UPC;
    float4 acc0 = {0.f, 0.f, 0.f, 0.f};
    float4 acc1 = {0.f, 0.f, 0.f, 0.f};
    float D0a = FLT_MAX, D1a = FLT_MAX, D2a = FLT_MAX;
    int   I0a = 0, I1a = 0, I2a = 0;
    float D0b = FLT_MAX, D1b = FLT_MAX, D2b = FLT_MAX;
    int   I0b = 0, I1b = 0, I2b = 0;

    static_assert(NCHUNK == UPC / 16, "merge interleave assumes 8 super-steps");
    #pragma unroll 1
    for (int ss = 0; ss < NCHUNK; ++ss) {          // 8 super-steps, no hoist
        const int kb = ss * 16;
        float4 a0b[4], a1b[4];
        #pragma unroll
        for (int i = 0; i < 4; ++i) {              // 8 A-loads in flight
            a0b[i] = *(const float4*)(A0 + kb + 4 * i);
            a1b[i] = *(const float4*)(A1 + kb + 4 * i);
        }
        const float2* pa = part + (ss * M_UP + q0) * 3;
        const float2* pb = part + (ss * M_UP + q1) * 3;
        float2 va0 = pa[0], va1 = pa[1], va2 = pa[2];
        float2 vb0 = pb[0], vb1 = pb[1], vb2 = pb[2];
        #pragma unroll
        for (int i = 0; i < 4; ++i) {
            const int k = kb + 4 * i;
            const float4* wp = (const float4*)(WT + k * OUTC) + c4;
            float4 w0 = wp[0], w1 = wp[32], w2 = wp[64], w3 = wp[96];
            fma4(acc0, a0b[i].x, w0); fma4(acc0, a0b[i].y, w1);
            fma4(acc0, a0b[i].z, w2); fma4(acc0, a0b[i].w, w3);
            fma4(acc1, a1b[i].x, w0); fma4(acc1, a1b[i].y, w1);
            fma4(acc1, a1b[i].z, w2); fma4(acc1, a1b[i].w, w3);
        }
        top3_bl(va0.x, __float_as_int(va0.y), D0a, D1a, D2a, I0a, I1a, I2a);
        top3_bl(va1.x, __float_as_int(va1.y), D0a, D1a, D2a, I0a, I1a, I2a);
        top3_bl(va2.x, __float_as_int(va2.y), D0a, D1a, D2a, I0a, I1a, I2a);
        top3_bl(vb0.x, __float_as_int(vb0.y), D0b, D1b, D2b, I0b, I1b, I2b);
        top3_bl(vb1.x, __float_as_int(vb1.y), D0b, D1b, D2b, I0b, I1b, I2b);
        top3_bl(vb2.x, __float_as_int(vb2.y), D0b, D1b, D2b, I0b, I1b, I2b);
    }

    const float4 b = ((const float4*)bias)[c4];
    const float4* df4 = (const float4*)down_f;
    // issue all 6 gathers together (independent)
    float4 f0a = df4[I0a * 32 + c4];
    float4 f1a = df4[I1a * 32 + c4];
    float4 f2a = df4[I2a * 32 + c4];
    float4 f0b = df4[I0b * 32 + c4];
    float4 f1b = df4[I1b * 32 + c4];
    float4 f2b = df4[I2b * 32 + c4];

    {
        float r0 = 1.f / (D0a + 1e-8f);
        float r1 = 1.f / (D1a + 1e-8f);
        float r2 = 1.f / (D2a + 1e-8f);
        float rs = (r0 + r1) + r2;
        float w0 = r0 / rs, w1 = r1 / rs, w2 = r2 / rs;
        float4 res;
        res.x = acc0.x + b.x + fmaf(w0, f0a.x, fmaf(w1, f1a.x, w2 * f2a.x));
        res.y = acc0.y + b.y + fmaf(w0, f0a.y, fmaf(w1, f1a.y, w2 * f2a.y));
        res.z = acc0.z + b.z + fmaf(w0, f0a.z, fmaf(w1, f1a.z, w2 * f2a.z));
        res.w = acc0.w + b.w + fmaf(w0, f0a.w, fmaf(w1, f1a.w, w2 * f2a.w));
        ((float4*)out)[q0 * 32 + c4] = res;
    }
    {
        float r0 = 1.f / (D0b + 1e-8f);
        float r1 = 1.f / (D1b + 1e-8f);
        float r2 = 1.f / (D2b + 1e-8f);
        float rs = (r0 + r1) + r2;
        float w0 = r0 / rs, w1 = r1 / rs, w2 = r2 / rs;
        float4 res;
        res.x = acc1.x + b.x + fmaf(w0, f0b.x, fmaf(w1, f1b.x, w2 * f2b.x));
        res.y = acc1.y + b.y + fmaf(w0, f0b.y, fmaf(w1, f1b.y, w2 * f2b.y));
        res.z = acc1.z + b.z + fmaf(w0, f0b.z, fmaf(w1, f1b.z, w2 * f2b.z));
        res.w = acc1.w + b.w + fmaf(w0, f0b.w, fmaf(w1, f1b.w, w2 * f2b.w));
        ((float4*)out)[q1 * 32 + c4] = res;
    }
}

extern "C" void kernel_launch(void* const* d_in, const int* in_sizes, int n_in,
                              void* d_out, int out_size, void* d_ws, size_t ws_size,
                              hipStream_t stream) {
    const float* up_points     = (const float*)d_in[0];
    const float* up_features   = (const float*)d_in[1];
    const float* down_points   = (const float*)d_in[2];
    const float* down_features = (const float*)d_in[3];
    const float* W_up          = (const float*)d_in[4];
    const float* b_up          = (const float*)d_in[5];
    const float* W_down        = (const float*)d_in[6];
    const float* b_down        = (const float*)d_in[7];
    float* out = (float*)d_out;

    float* wt_down = (float*)d_ws;                         // 256*128
    float* wt_up   = wt_down + DOWNC * OUTC;               // 128*128
    float* down_f  = wt_up + UPC * OUTC;                   // 8192*128
    float2* part   = (float2*)(down_f + N_DOWN * OUTC);    // NCHUNK*32768*3 float2
    // total ~10.7 MB (same footprint as the proven R0 layout)

    transpose_w<<<(DOWNC * OUTC + UPC * OUTC) / 256, 256, 0, stream>>>(
        W_up, W_down, wt_up, wt_down);
    down_proj<<<N_DOWN / 16, 256, 0, stream>>>(
        down_features, wt_down, b_down, down_f);
    knn_partial<<<dim3(M_UP / (256 * Q), NCHUNK), 256, 0, stream>>>(
        up_points, down_points, part);
    up_fused<<<M_UP / 16, 256, 0, stream>>>(
        up_features, wt_up, b_up, down_f, part, out);
}

// Round 6
// 211.750 us; speedup vs baseline: 2.5042x; 1.2405x over previous
//
#include <hip/hip_runtime.h>
#include <cfloat>

#define M_UP   32768
#define N_DOWN 8192
#define UPC    128
#define DOWNC  256
#define OUTC   128
#define NCHUNK 8
#define CHUNK  (N_DOWN / NCHUNK)   // 1024
#define G      8                   // selection group size
#define Q      2                   // queries per thread (amortizes LDS reads)

__device__ __forceinline__ void fma4(float4& acc, float s, const float4 w) {
    acc.x = fmaf(s, w.x, acc.x);
    acc.y = fmaf(s, w.y, acc.y);
    acc.z = fmaf(s, w.z, acc.z);
    acc.w = fmaf(s, w.w, acc.w);
}

// Branchless stable top-3 insert with index tracking.
// Strict < everywhere => earlier-inserted wins ties (stable in scan order),
// matching jax.lax.top_k's lower-index-first tie-break.
__device__ __forceinline__ void top3_bl(float s, int idx,
                                        float& d0, float& d1, float& d2,
                                        int& i0, int& i1, int& i2) {
    bool c0 = s < d0, c1 = s < d1, c2 = s < d2;
    float n0 = fminf(d0, s);
    float n1 = __builtin_amdgcn_fmed3f(d0, d1, s);
    float n2 = __builtin_amdgcn_fmed3f(d1, d2, s);
    int m0 = c0 ? idx : i0;
    int m1 = c0 ? i0 : (c1 ? idx : i1);
    int m2 = c1 ? i1 : (c2 ? idx : i2);
    d0 = n0; d1 = n1; d2 = n2;
    i0 = m0; i1 = m1; i2 = m2;
}

// ---------------------------------------------------------------------------
// K0: transpose weights for coalesced float4 GEMM reads.
// ---------------------------------------------------------------------------
__global__ __launch_bounds__(256) void transpose_w(
        const float* __restrict__ W_up, const float* __restrict__ W_down,
        float* __restrict__ wt_up, float* __restrict__ wt_down) {
    int e = blockIdx.x * 256 + threadIdx.x;
    if (e < DOWNC * OUTC) {
        int k = e >> 7, c = e & 127;
        wt_down[e] = W_down[c * DOWNC + k];
    } else {
        int e2 = e - DOWNC * OUTC;
        int k = e2 >> 7, c = e2 & 127;
        wt_up[e2] = W_up[c * UPC + k];
    }
}

// ---------------------------------------------------------------------------
// K1: down_f = down_features @ W_down.T + b_down  (8192 x 128)
// R3-R5 lesson: per-k-step global A loads are latency-serialized (vmcnt(0)
// drain each step); register batching spills (R4/R5). Fix: stage the
// contiguous 16-row A-tile in LDS once (coalesced, one exposed latency),
// then k-loop reads A via broadcast ds_read_b128 which the compiler
// pipelines with fine lgkmcnt. Only W stays global (2KB/step, L2-hit,
// shared by all waves).
// ---------------------------------------------------------------------------
__global__ __launch_bounds__(256) void down_proj(
        const float* __restrict__ A, const float* __restrict__ WT,
        const float* __restrict__ bias, float* __restrict__ down_f) {
    __shared__ __align__(16) float sA[16 * DOWNC];          // 16 KB
    {
        const float4* Ab4 = (const float4*)(A + blockIdx.x * 16 * DOWNC);
        float4* sA4 = (float4*)sA;
        #pragma unroll
        for (int i = 0; i < 4; ++i)                         // 4 loads in flight
            sA4[threadIdx.x + i * 256] = Ab4[threadIdx.x + i * 256];
    }
    __syncthreads();
    const int c4 = threadIdx.x & 31;
    const int rr = threadIdx.x >> 5;
    float4 acc0 = {0.f, 0.f, 0.f, 0.f};
    float4 acc1 = {0.f, 0.f, 0.f, 0.f};
    #pragma unroll 2
    for (int k = 0; k < DOWNC; k += 4) {
        float4 a0 = *(const float4*)&sA[rr * DOWNC + k];
        float4 a1 = *(const float4*)&sA[(rr + 8) * DOWNC + k];
        const float4* wp = (const float4*)(WT + k * OUTC) + c4;
        float4 w0 = wp[0], w1 = wp[32], w2 = wp[64], w3 = wp[96];
        fma4(acc0, a0.x, w0); fma4(acc0, a0.y, w1);
        fma4(acc0, a0.z, w2); fma4(acc0, a0.w, w3);
        fma4(acc1, a1.x, w0); fma4(acc1, a1.y, w1);
        fma4(acc1, a1.z, w2); fma4(acc1, a1.w, w3);
    }
    const int r0 = blockIdx.x * 16 + rr;
    const int r1 = r0 + 8;
    float4 b = ((const float4*)bias)[c4];
    acc0.x += b.x; acc0.y += b.y; acc0.z += b.z; acc0.w += b.w;
    acc1.x += b.x; acc1.y += b.y; acc1.z += b.z; acc1.w += b.w;
    ((float4*)down_f)[r0 * 32 + c4] = acc0;
    ((float4*)down_f)[r1 * 32 + c4] = acc1;
}

// ---------------------------------------------------------------------------
// K2: partial 3-NN (unchanged — verified ~80us). Q=2 queries/thread + SoA
// LDS chunk. Group-min top-3 selection + exact refine of <=3 winning groups
// per query. Partials stored as (d, idx-as-float) float2 pairs.
// ---------------------------------------------------------------------------
__global__ __launch_bounds__(256) void knn_partial(
        const float* __restrict__ up_points,
        const float* __restrict__ down_points,
        float2* __restrict__ part) {            // [NCHUNK][M_UP][3]
    __shared__ __align__(16) float sx[CHUNK];
    __shared__ __align__(16) float sy[CHUNK];
    __shared__ __align__(16) float sz[CHUNK];
    const int base = blockIdx.y * CHUNK;
    for (int t = threadIdx.x; t < CHUNK; t += 256) {
        int g = base + t;
        sx[t] = down_points[3 * g];
        sy[t] = down_points[3 * g + 1];
        sz[t] = down_points[3 * g + 2];
    }
    __syncthreads();

    const int m0 = blockIdx.x * (256 * Q) + threadIdx.x;
    const int m1 = m0 + 256;
    const float q0x = up_points[3 * m0];
    const float q0y = up_points[3 * m0 + 1];
    const float q0z = up_points[3 * m0 + 2];
    const float q1x = up_points[3 * m1];
    const float q1y = up_points[3 * m1 + 1];
    const float q1z = up_points[3 * m1 + 2];

    float a_gd0 = FLT_MAX, a_gd1 = FLT_MAX, a_gd2 = FLT_MAX;
    int   a_gi0 = 0, a_gi1 = 0, a_gi2 = 0;
    float b_gd0 = FLT_MAX, b_gd1 = FLT_MAX, b_gd2 = FLT_MAX;
    int   b_gi0 = 0, b_gi1 = 0, b_gi2 = 0;

    for (int g = 0; g < CHUNK; g += G) {
        float4 x0 = *(const float4*)&sx[g], x1 = *(const float4*)&sx[g + 4];
        float4 y0 = *(const float4*)&sy[g], y1 = *(const float4*)&sy[g + 4];
        float4 z0 = *(const float4*)&sz[g], z1 = *(const float4*)&sz[g + 4];
        float px[G] = {x0.x, x0.y, x0.z, x0.w, x1.x, x1.y, x1.z, x1.w};
        float py[G] = {y0.x, y0.y, y0.z, y0.w, y1.x, y1.y, y1.z, y1.w};
        float pz[G] = {z0.x, z0.y, z0.z, z0.w, z1.x, z1.y, z1.z, z1.w};
        float s0[G], s1[G];
        #pragma unroll
        for (int j = 0; j < G; ++j) {
            float dx0 = q0x - px[j], dy0 = q0y - py[j], dz0 = q0z - pz[j];
            s0[j] = fmaf(dz0, dz0, fmaf(dy0, dy0, dx0 * dx0));
            float dx1 = q1x - px[j], dy1 = q1y - py[j], dz1 = q1z - pz[j];
            s1[j] = fmaf(dz1, dz1, fmaf(dy1, dy1, dx1 * dx1));
        }
        float gm0 = fminf(fminf(fminf(s0[0], s0[1]), fminf(s0[2], s0[3])),
                          fminf(fminf(s0[4], s0[5]), fminf(s0[6], s0[7])));
        float gm1 = fminf(fminf(fminf(s1[0], s1[1]), fminf(s1[2], s1[3])),
                          fminf(fminf(s1[4], s1[5]), fminf(s1[6], s1[7])));
        top3_bl(gm0, g, a_gd0, a_gd1, a_gd2, a_gi0, a_gi1, a_gi2);
        top3_bl(gm1, g, b_gd0, b_gd1, b_gd2, b_gi0, b_gi1, b_gi2);
    }

    // exact refine over the 3 winning groups (24 points per query)
    #pragma unroll
    for (int qq = 0; qq < Q; ++qq) {
        const float qx = qq ? q1x : q0x;
        const float qy = qq ? q1y : q0y;
        const float qz = qq ? q1z : q0z;
        int bases[3];
        if (qq == 0) { bases[0] = a_gi0; bases[1] = a_gi1; bases[2] = a_gi2; }
        else         { bases[0] = b_gi0; bases[1] = b_gi1; bases[2] = b_gi2; }
        float D0 = FLT_MAX, D1 = FLT_MAX, D2 = FLT_MAX;
        int I0 = 0, I1 = 0, I2 = 0;
        #pragma unroll
        for (int t = 0; t < 3; ++t) {
            const int b = bases[t];
            float4 x0 = *(const float4*)&sx[b], x1 = *(const float4*)&sx[b + 4];
            float4 y0 = *(const float4*)&sy[b], y1 = *(const float4*)&sy[b + 4];
            float4 z0 = *(const float4*)&sz[b], z1 = *(const float4*)&sz[b + 4];
            float px[G] = {x0.x, x0.y, x0.z, x0.w, x1.x, x1.y, x1.z, x1.w};
            float py[G] = {y0.x, y0.y, y0.z, y0.w, y1.x, y1.y, y1.z, y1.w};
            float pz[G] = {z0.x, z0.y, z0.z, z0.w, z1.x, z1.y, z1.z, z1.w};
            #pragma unroll
            for (int j = 0; j < G; ++j) {
                float dx = qx - px[j], dy = qy - py[j], dz = qz - pz[j];
                float s = fmaf(dz, dz, fmaf(dy, dy, dx * dx));
                top3_bl(s, base + b + j, D0, D1, D2, I0, I1, I2);
            }
        }
        const int m = qq ? m1 : m0;
        const int o = (blockIdx.y * M_UP + m) * 3;
        part[o]     = make_float2(D0, __int_as_float(I0));
        part[o + 1] = make_float2(D1, __int_as_float(I1));
        part[o + 2] = make_float2(D2, __int_as_float(I2));
    }
}

// ---------------------------------------------------------------------------
// K3: fused up-projection + top-3 merge + interpolation + bias + add.
// GEMM part restructured like down_proj: 16-row A-tile staged in LDS (8KB,
// contiguous), k-loop reads A via broadcast ds_read_b128 (lgkmcnt-pipelined)
// + 4 W loads (L2). Merge/gather epilogue reverted to the R3 form (proven,
// no spill at VGPR 36). No launch_bounds cap, no register load-batches.
// ---------------------------------------------------------------------------
__global__ __launch_bounds__(256) void up_fused(
        const float* __restrict__ A, const float* __restrict__ WT,
        const float* __restrict__ bias, const float* __restrict__ down_f,
        const float2* __restrict__ part,
        float* __restrict__ out) {
    __shared__ __align__(16) float sA[16 * UPC];            // 8 KB
    {
        const float4* Ab4 = (const float4*)(A + blockIdx.x * 16 * UPC);
        float4* sA4 = (float4*)sA;
        #pragma unroll
        for (int i = 0; i < 2; ++i)                         // 2 loads in flight
            sA4[threadIdx.x + i * 256] = Ab4[threadIdx.x + i * 256];
    }
    __syncthreads();
    const int c4 = threadIdx.x & 31;
    const int rr = threadIdx.x >> 5;
    const int q0 = blockIdx.x * 16 + rr;
    const int q1 = q0 + 8;
    float4 acc0 = {0.f, 0.f, 0.f, 0.f};
    float4 acc1 = {0.f, 0.f, 0.f, 0.f};
    #pragma unroll 2
    for (int k = 0; k < UPC; k += 4) {
        float4 a0 = *(const float4*)&sA[rr * UPC + k];
        float4 a1 = *(const float4*)&sA[(rr + 8) * UPC + k];
        const float4* wp = (const float4*)(WT + k * OUTC) + c4;
        float4 w0 = wp[0], w1 = wp[32], w2 = wp[64], w3 = wp[96];
        fma4(acc0, a0.x, w0); fma4(acc0, a0.y, w1);
        fma4(acc0, a0.z, w2); fma4(acc0, a0.w, w3);
        fma4(acc1, a1.x, w0); fma4(acc1, a1.y, w1);
        fma4(acc1, a1.z, w2); fma4(acc1, a1.w, w3);
    }
    const float4 b = ((const float4*)bias)[c4];
    const float4* df4 = (const float4*)down_f;
    #pragma unroll
    for (int t = 0; t < 2; ++t) {
        const int q = t ? q1 : q0;
        float4 acc = t ? acc1 : acc0;
        float D0 = FLT_MAX, D1 = FLT_MAX, D2 = FLT_MAX;
        int I0 = 0, I1 = 0, I2 = 0;
        #pragma unroll
        for (int s = 0; s < NCHUNK; ++s) {
            const float2* p = part + (s * M_UP + q) * 3;
            #pragma unroll
            for (int j = 0; j < 3; ++j) {
                float2 v = p[j];
                top3_bl(v.x, __float_as_int(v.y), D0, D1, D2, I0, I1, I2);
            }
        }
        float r0 = 1.f / (D0 + 1e-8f);
        float r1 = 1.f / (D1 + 1e-8f);
        float r2 = 1.f / (D2 + 1e-8f);
        float rs = (r0 + r1) + r2;
        float w0 = r0 / rs, w1 = r1 / rs, w2 = r2 / rs;
        float4 f0 = df4[I0 * 32 + c4];
        float4 f1 = df4[I1 * 32 + c4];
        float4 f2 = df4[I2 * 32 + c4];
        float4 res;
        res.x = acc.x + b.x + fmaf(w0, f0.x, fmaf(w1, f1.x, w2 * f2.x));
        res.y = acc.y + b.y + fmaf(w0, f0.y, fmaf(w1, f1.y, w2 * f2.y));
        res.z = acc.z + b.z + fmaf(w0, f0.z, fmaf(w1, f1.z, w2 * f2.z));
        res.w = acc.w + b.w + fmaf(w0, f0.w, fmaf(w1, f1.w, w2 * f2.w));
        ((float4*)out)[q * 32 + c4] = res;
    }
}

extern "C" void kernel_launch(void* const* d_in, const int* in_sizes, int n_in,
                              void* d_out, int out_size, void* d_ws, size_t ws_size,
                              hipStream_t stream) {
    const float* up_points     = (const float*)d_in[0];
    const float* up_features   = (const float*)d_in[1];
    const float* down_points   = (const float*)d_in[2];
    const float* down_features = (const float*)d_in[3];
    const float* W_up          = (const float*)d_in[4];
    const float* b_up          = (const float*)d_in[5];
    const float* W_down        = (const float*)d_in[6];
    const float* b_down        = (const float*)d_in[7];
    float* out = (float*)d_out;

    float* wt_down = (float*)d_ws;                         // 256*128
    float* wt_up   = wt_down + DOWNC * OUTC;               // 128*128
    float* down_f  = wt_up + UPC * OUTC;                   // 8192*128
    float2* part   = (float2*)(down_f + N_DOWN * OUTC);    // NCHUNK*32768*3 float2
    // total ~10.7 MB (same footprint as the proven R0 layout)

    transpose_w<<<(DOWNC * OUTC + UPC * OUTC) / 256, 256, 0, stream>>>(
        W_up, W_down, wt_up, wt_down);
    down_proj<<<N_DOWN / 16, 256, 0, stream>>>(
        down_features, wt_down, b_down, down_f);
    knn_partial<<<dim3(M_UP / (256 * Q), NCHUNK), 256, 0, stream>>>(
        up_points, down_points, part);
    up_fused<<<M_UP / 16, 256, 0, stream>>>(
        up_features, wt_up, b_up, down_f, part, out);
}

// Round 7
// 196.639 us; speedup vs baseline: 2.6967x; 1.0768x over previous
//
#include <hip/hip_runtime.h>
#include <cfloat>

#define M_UP   32768
#define N_DOWN 8192
#define UPC    128
#define DOWNC  256
#define OUTC   128
#define NCHUNK 8
#define CHUNK  (N_DOWN / NCHUNK)   // 1024
#define G      8                   // selection group size
#define Q      2                   // queries per thread (amortizes LDS reads)
#define PG     12                  // padded group stride in floats (48B): group
                                   // bases hit 8 distinct bank-start positions
                                   // -> refine bank conflicts ~eliminated

__device__ __forceinline__ void fma4(float4& acc, float s, const float4 w) {
    acc.x = fmaf(s, w.x, acc.x);
    acc.y = fmaf(s, w.y, acc.y);
    acc.z = fmaf(s, w.z, acc.z);
    acc.w = fmaf(s, w.w, acc.w);
}

// Branchless stable top-3 insert with index tracking.
// Strict < everywhere => earlier-inserted wins ties (stable in scan order),
// matching jax.lax.top_k's lower-index-first tie-break.
__device__ __forceinline__ void top3_bl(float s, int idx,
                                        float& d0, float& d1, float& d2,
                                        int& i0, int& i1, int& i2) {
    bool c0 = s < d0, c1 = s < d1, c2 = s < d2;
    float n0 = fminf(d0, s);
    float n1 = __builtin_amdgcn_fmed3f(d0, d1, s);
    float n2 = __builtin_amdgcn_fmed3f(d1, d2, s);
    int m0 = c0 ? idx : i0;
    int m1 = c0 ? i0 : (c1 ? idx : i1);
    int m2 = c1 ? i1 : (c2 ? idx : i2);
    d0 = n0; d1 = n1; d2 = n2;
    i0 = m0; i1 = m1; i2 = m2;
}

// ---------------------------------------------------------------------------
// K0: transpose weights for coalesced float4 GEMM reads.
// ---------------------------------------------------------------------------
__global__ __launch_bounds__(256) void transpose_w(
        const float* __restrict__ W_up, const float* __restrict__ W_down,
        float* __restrict__ wt_up, float* __restrict__ wt_down) {
    int e = blockIdx.x * 256 + threadIdx.x;
    if (e < DOWNC * OUTC) {
        int k = e >> 7, c = e & 127;
        wt_down[e] = W_down[c * DOWNC + k];
    } else {
        int e2 = e - DOWNC * OUTC;
        int k = e2 >> 7, c = e2 & 127;
        wt_up[e2] = W_up[c * UPC + k];
    }
}

// ---------------------------------------------------------------------------
// K1: down_f = down_features @ W_down.T + b_down  (8192 x 128)
// R7: ALL operands in LDS. A-tile (16KB) staged once; W staged in 32KB
// quarter-panels (4 phases) -> zero global loads in the k-loop, no vmcnt
// drains; compiler pipelines ds_read via fine lgkmcnt. 48KB LDS total.
// ---------------------------------------------------------------------------
__global__ __launch_bounds__(256) void down_proj(
        const float* __restrict__ A, const float* __restrict__ WT,
        const float* __restrict__ bias, float* __restrict__ down_f) {
    __shared__ __align__(16) float sA[16 * DOWNC];          // 16 KB
    __shared__ __align__(16) float sW[64 * OUTC];           // 32 KB
    {
        const float4* Ab4 = (const float4*)(A + blockIdx.x * 16 * DOWNC);
        float4* sA4 = (float4*)sA;
        #pragma unroll
        for (int i = 0; i < 4; ++i)
            sA4[threadIdx.x + i * 256] = Ab4[threadIdx.x + i * 256];
    }
    const int c4 = threadIdx.x & 31;
    const int rr = threadIdx.x >> 5;
    float4 acc0 = {0.f, 0.f, 0.f, 0.f};
    float4 acc1 = {0.f, 0.f, 0.f, 0.f};
    for (int kh = 0; kh < 4; ++kh) {                        // 64 k per phase
        if (kh) __syncthreads();                            // drain prev sW readers
        {
            const float4* W4 = (const float4*)(WT + kh * 64 * OUTC);
            float4* sW4 = (float4*)sW;
            #pragma unroll
            for (int i = 0; i < 8; ++i)
                sW4[threadIdx.x + i * 256] = W4[threadIdx.x + i * 256];
        }
        __syncthreads();
        #pragma unroll 2
        for (int k2 = 0; k2 < 64; k2 += 4) {
            const int k = kh * 64 + k2;
            float4 a0 = *(const float4*)&sA[rr * DOWNC + k];
            float4 a1 = *(const float4*)&sA[(rr + 8) * DOWNC + k];
            const float4* wp = (const float4*)(sW + k2 * OUTC) + c4;
            float4 w0 = wp[0], w1 = wp[32], w2 = wp[64], w3 = wp[96];
            fma4(acc0, a0.x, w0); fma4(acc0, a0.y, w1);
            fma4(acc0, a0.z, w2); fma4(acc0, a0.w, w3);
            fma4(acc1, a1.x, w0); fma4(acc1, a1.y, w1);
            fma4(acc1, a1.z, w2); fma4(acc1, a1.w, w3);
        }
    }
    const int r0 = blockIdx.x * 16 + rr;
    const int r1 = r0 + 8;
    float4 b = ((const float4*)bias)[c4];
    acc0.x += b.x; acc0.y += b.y; acc0.z += b.z; acc0.w += b.w;
    acc1.x += b.x; acc1.y += b.y; acc1.z += b.z; acc1.w += b.w;
    ((float4*)down_f)[r0 * 32 + c4] = acc0;
    ((float4*)down_f)[r1 * 32 + c4] = acc1;
}

// ---------------------------------------------------------------------------
// K2: partial 3-NN. Q=2 + SoA (verified 67.5us). R7 adds padded group
// stride PG=12 floats: scan reads stay uniform-broadcast (conflict-free);
// refine's divergent group-base reads now start at 8 distinct bank
// positions covering all 32 banks (was 4 of 32 -> 5.04M conflict cycles).
// ---------------------------------------------------------------------------
__global__ __launch_bounds__(256) void knn_partial(
        const float* __restrict__ up_points,
        const float* __restrict__ down_points,
        float2* __restrict__ part) {            // [NCHUNK][M_UP][3]
    __shared__ __align__(16) float sx[PG * (CHUNK / G)];    // 6 KB
    __shared__ __align__(16) float sy[PG * (CHUNK / G)];
    __shared__ __align__(16) float sz[PG * (CHUNK / G)];
    const int base = blockIdx.y * CHUNK;
    for (int t = threadIdx.x; t < CHUNK; t += 256) {
        int g = base + t;
        int gi = t >> 3, j = t & 7;
        sx[PG * gi + j] = down_points[3 * g];
        sy[PG * gi + j] = down_points[3 * g + 1];
        sz[PG * gi + j] = down_points[3 * g + 2];
    }
    __syncthreads();

    const int m0 = blockIdx.x * (256 * Q) + threadIdx.x;
    const int m1 = m0 + 256;
    const float q0x = up_points[3 * m0];
    const float q0y = up_points[3 * m0 + 1];
    const float q0z = up_points[3 * m0 + 2];
    const float q1x = up_points[3 * m1];
    const float q1y = up_points[3 * m1 + 1];
    const float q1z = up_points[3 * m1 + 2];

    float a_gd0 = FLT_MAX, a_gd1 = FLT_MAX, a_gd2 = FLT_MAX;
    int   a_gi0 = 0, a_gi1 = 0, a_gi2 = 0;
    float b_gd0 = FLT_MAX, b_gd1 = FLT_MAX, b_gd2 = FLT_MAX;
    int   b_gi0 = 0, b_gi1 = 0, b_gi2 = 0;

    for (int gi = 0; gi < CHUNK / G; ++gi) {
        float4 x0 = *(const float4*)&sx[PG * gi], x1 = *(const float4*)&sx[PG * gi + 4];
        float4 y0 = *(const float4*)&sy[PG * gi], y1 = *(const float4*)&sy[PG * gi + 4];
        float4 z0 = *(const float4*)&sz[PG * gi], z1 = *(const float4*)&sz[PG * gi + 4];
        float px[G] = {x0.x, x0.y, x0.z, x0.w, x1.x, x1.y, x1.z, x1.w};
        float py[G] = {y0.x, y0.y, y0.z, y0.w, y1.x, y1.y, y1.z, y1.w};
        float pz[G] = {z0.x, z0.y, z0.z, z0.w, z1.x, z1.y, z1.z, z1.w};
        float s0[G], s1[G];
        #pragma unroll
        for (int j = 0; j < G; ++j) {
            float dx0 = q0x - px[j], dy0 = q0y - py[j], dz0 = q0z - pz[j];
            s0[j] = fmaf(dz0, dz0, fmaf(dy0, dy0, dx0 * dx0));
            float dx1 = q1x - px[j], dy1 = q1y - py[j], dz1 = q1z - pz[j];
            s1[j] = fmaf(dz1, dz1, fmaf(dy1, dy1, dx1 * dx1));
        }
        float gm0 = fminf(fminf(fminf(s0[0], s0[1]), fminf(s0[2], s0[3])),
                          fminf(fminf(s0[4], s0[5]), fminf(s0[6], s0[7])));
        float gm1 = fminf(fminf(fminf(s1[0], s1[1]), fminf(s1[2], s1[3])),
                          fminf(fminf(s1[4], s1[5]), fminf(s1[6], s1[7])));
        top3_bl(gm0, gi, a_gd0, a_gd1, a_gd2, a_gi0, a_gi1, a_gi2);
        top3_bl(gm1, gi, b_gd0, b_gd1, b_gd2, b_gi0, b_gi1, b_gi2);
    }

    // exact refine over the 3 winning groups (24 points per query)
    #pragma unroll
    for (int qq = 0; qq < Q; ++qq) {
        const float qx = qq ? q1x : q0x;
        const float qy = qq ? q1y : q0y;
        const float qz = qq ? q1z : q0z;
        int bases[3];
        if (qq == 0) { bases[0] = a_gi0; bases[1] = a_gi1; bases[2] = a_gi2; }
        else         { bases[0] = b_gi0; bases[1] = b_gi1; bases[2] = b_gi2; }
        float D0 = FLT_MAX, D1 = FLT_MAX, D2 = FLT_MAX;
        int I0 = 0, I1 = 0, I2 = 0;
        #pragma unroll
        for (int t = 0; t < 3; ++t) {
            const int gb = bases[t];
            float4 x0 = *(const float4*)&sx[PG * gb], x1 = *(const float4*)&sx[PG * gb + 4];
            float4 y0 = *(const float4*)&sy[PG * gb], y1 = *(const float4*)&sy[PG * gb + 4];
            float4 z0 = *(const float4*)&sz[PG * gb], z1 = *(const float4*)&sz[PG * gb + 4];
            float px[G] = {x0.x, x0.y, x0.z, x0.w, x1.x, x1.y, x1.z, x1.w};
            float py[G] = {y0.x, y0.y, y0.z, y0.w, y1.x, y1.y, y1.z, y1.w};
            float pz[G] = {z0.x, z0.y, z0.z, z0.w, z1.x, z1.y, z1.z, z1.w};
            #pragma unroll
            for (int j = 0; j < G; ++j) {
                float dx = qx - px[j], dy = qy - py[j], dz = qz - pz[j];
                float s = fmaf(dz, dz, fmaf(dy, dy, dx * dx));
                top3_bl(s, base + gb * G + j, D0, D1, D2, I0, I1, I2);
            }
        }
        const int m = qq ? m1 : m0;
        const int o = (blockIdx.y * M_UP + m) * 3;
        part[o]     = make_float2(D0, __int_as_float(I0));
        part[o + 1] = make_float2(D1, __int_as_float(I1));
        part[o + 2] = make_float2(D2, __int_as_float(I2));
    }
}

// ---------------------------------------------------------------------------
// K3: fused up-projection + top-3 merge + interpolation + bias + add.
// R7: ALL GEMM operands in LDS. A-tile 8KB staged once; W staged in 32KB
// half-panels (2 phases) -> zero global loads in the k-loop. 40KB LDS.
// Merge/gather epilogue unchanged (proven).
// ---------------------------------------------------------------------------
__global__ __launch_bounds__(256) void up_fused(
        const float* __restrict__ A, const float* __restrict__ WT,
        const float* __restrict__ bias, const float* __restrict__ down_f,
        const float2* __restrict__ part,
        float* __restrict__ out) {
    __shared__ __align__(16) float sA[16 * UPC];            // 8 KB
    __shared__ __align__(16) float sW[64 * OUTC];           // 32 KB
    {
        const float4* Ab4 = (const float4*)(A + blockIdx.x * 16 * UPC);
        float4* sA4 = (float4*)sA;
        #pragma unroll
        for (int i = 0; i < 2; ++i)
            sA4[threadIdx.x + i * 256] = Ab4[threadIdx.x + i * 256];
    }
    const int c4 = threadIdx.x & 31;
    const int rr = threadIdx.x >> 5;
    const int q0 = blockIdx.x * 16 + rr;
    const int q1 = q0 + 8;
    float4 acc0 = {0.f, 0.f, 0.f, 0.f};
    float4 acc1 = {0.f, 0.f, 0.f, 0.f};
    for (int kh = 0; kh < 2; ++kh) {                        // 64 k per phase
        if (kh) __syncthreads();                            // drain prev sW readers
        {
            const float4* W4 = (const float4*)(WT + kh * 64 * OUTC);
            float4* sW4 = (float4*)sW;
            #pragma unroll
            for (int i = 0; i < 8; ++i)
                sW4[threadIdx.x + i * 256] = W4[threadIdx.x + i * 256];
        }
        __syncthreads();
        #pragma unroll 2
        for (int k2 = 0; k2 < 64; k2 += 4) {
            const int k = kh * 64 + k2;
            float4 a0 = *(const float4*)&sA[rr * UPC + k];
            float4 a1 = *(const float4*)&sA[(rr + 8) * UPC + k];
            const float4* wp = (const float4*)(sW + k2 * OUTC) + c4;
            float4 w0 = wp[0], w1 = wp[32], w2 = wp[64], w3 = wp[96];
            fma4(acc0, a0.x, w0); fma4(acc0, a0.y, w1);
            fma4(acc0, a0.z, w2); fma4(acc0, a0.w, w3);
            fma4(acc1, a1.x, w0); fma4(acc1, a1.y, w1);
            fma4(acc1, a1.z, w2); fma4(acc1, a1.w, w3);
        }
    }
    const float4 b = ((const float4*)bias)[c4];
    const float4* df4 = (const float4*)down_f;
    #pragma unroll
    for (int t = 0; t < 2; ++t) {
        const int q = t ? q1 : q0;
        float4 acc = t ? acc1 : acc0;
        float D0 = FLT_MAX, D1 = FLT_MAX, D2 = FLT_MAX;
        int I0 = 0, I1 = 0, I2 = 0;
        #pragma unroll
        for (int s = 0; s < NCHUNK; ++s) {
            const float2* p = part + (s * M_UP + q) * 3;
            #pragma unroll
            for (int j = 0; j < 3; ++j) {
                float2 v = p[j];
                top3_bl(v.x, __float_as_int(v.y), D0, D1, D2, I0, I1, I2);
            }
        }
        float r0 = 1.f / (D0 + 1e-8f);
        float r1 = 1.f / (D1 + 1e-8f);
        float r2 = 1.f / (D2 + 1e-8f);
        float rs = (r0 + r1) + r2;
        float w0 = r0 / rs, w1 = r1 / rs, w2 = r2 / rs;
        float4 f0 = df4[I0 * 32 + c4];
        float4 f1 = df4[I1 * 32 + c4];
        float4 f2 = df4[I2 * 32 + c4];
        float4 res;
        res.x = acc.x + b.x + fmaf(w0, f0.x, fmaf(w1, f1.x, w2 * f2.x));
        res.y = acc.y + b.y + fmaf(w0, f0.y, fmaf(w1, f1.y, w2 * f2.y));
        res.z = acc.z + b.z + fmaf(w0, f0.z, fmaf(w1, f1.z, w2 * f2.z));
        res.w = acc.w + b.w + fmaf(w0, f0.w, fmaf(w1, f1.w, w2 * f2.w));
        ((float4*)out)[q * 32 + c4] = res;
    }
}

extern "C" void kernel_launch(void* const* d_in, const int* in_sizes, int n_in,
                              void* d_out, int out_size, void* d_ws, size_t ws_size,
                              hipStream_t stream) {
    const float* up_points     = (const float*)d_in[0];
    const float* up_features   = (const float*)d_in[1];
    const float* down_points   = (const float*)d_in[2];
    const float* down_features = (const float*)d_in[3];
    const float* W_up          = (const float*)d_in[4];
    const float* b_up          = (const float*)d_in[5];
    const float* W_down        = (const float*)d_in[6];
    const float* b_down        = (const float*)d_in[7];
    float* out = (float*)d_out;

    float* wt_down = (float*)d_ws;                         // 256*128
    float* wt_up   = wt_down + DOWNC * OUTC;               // 128*128
    float* down_f  = wt_up + UPC * OUTC;                   // 8192*128
    float2* part   = (float2*)(down_f + N_DOWN * OUTC);    // NCHUNK*32768*3 float2
    // total ~10.7 MB (same footprint as the proven R0 layout)

    transpose_w<<<(DOWNC * OUTC + UPC * OUTC) / 256, 256, 0, stream>>>(
        W_up, W_down, wt_up, wt_down);
    down_proj<<<N_DOWN / 16, 256, 0, stream>>>(
        down_features, wt_down, b_down, down_f);
    knn_partial<<<dim3(M_UP / (256 * Q), NCHUNK), 256, 0, stream>>>(
        up_points, down_points, part);
    up_fused<<<M_UP / 16, 256, 0, stream>>>(
        up_features, wt_up, b_up, down_f, part, out);
}